// Round 6
// baseline (328.009 us; speedup 1.0000x reference)
//
#include <hip/hip_runtime.h>
#include <hip/hip_bf16.h>
#include <math.h>

#define DIMF 256   // feature dim (d = h = 256)

typedef __attribute__((ext_vector_type(8))) short s16x8;
typedef __attribute__((ext_vector_type(4))) float f32x4;
typedef __attribute__((ext_vector_type(8))) unsigned short u16x8;

__device__ __forceinline__ float bf2f(unsigned short u) {
    return __uint_as_float(((unsigned)u) << 16);
}
__device__ __forceinline__ unsigned short f2bf(float f) {  // RNE
    unsigned u = __float_as_uint(f);
    u += 0x7FFFu + ((u >> 16) & 1u);
    return (unsigned short)(u >> 16);
}
__device__ __forceinline__ void split1(float f, unsigned short& h, unsigned short& l) {
    unsigned u = __float_as_uint(f);
    h = (unsigned short)(u >> 16);
    float r = f - __uint_as_float(u & 0xFFFF0000u);
    l = (unsigned short)(__float_as_uint(r) >> 16);
}

// ---------------------------------------------------------------------------
// CSR build
// ---------------------------------------------------------------------------
__global__ __launch_bounds__(256) void hist_kernel(const int* __restrict__ dst,
                                                   int* __restrict__ indeg, int E) {
    int e = blockIdx.x * 256 + threadIdx.x;
    if (e < E) atomicAdd(&indeg[dst[e]], 1);
}

__global__ __launch_bounds__(256) void scan_partial(const int* __restrict__ indeg,
                                                    int* __restrict__ blockSums, int n) {
    int t = threadIdx.x;
    int base = blockIdx.x * 1024 + t * 4;
    int s = 0;
#pragma unroll
    for (int j = 0; j < 4; ++j) { int i = base + j; if (i < n) s += indeg[i]; }
#pragma unroll
    for (int off = 32; off > 0; off >>= 1) s += __shfl_down(s, off);
    __shared__ int sm[4];
    if ((t & 63) == 0) sm[t >> 6] = s;
    __syncthreads();
    if (t == 0) blockSums[blockIdx.x] = sm[0] + sm[1] + sm[2] + sm[3];
}

__global__ __launch_bounds__(64) void scan_sums(int* __restrict__ blockSums, int nb) {
    int t = threadIdx.x;
    int carry = 0;
    for (int base = 0; base < nb; base += 64) {
        int i = base + t;
        int v = (i < nb) ? blockSums[i] : 0;
        int x = v;
#pragma unroll
        for (int off = 1; off < 64; off <<= 1) {
            int y = __shfl_up(x, off);
            if (t >= off) x += y;
        }
        if (i < nb) blockSums[i] = carry + x - v;  // exclusive
        carry += __shfl(x, 63);
    }
}

// scan_final also emits dinv (folded dinv_kernel)
__global__ __launch_bounds__(256) void scan_final(const int* __restrict__ indeg,
                                                  const int* __restrict__ blockOffs,
                                                  int* __restrict__ rowptr,
                                                  int* __restrict__ cursor,
                                                  float* __restrict__ dinv, int n) {
    __shared__ int waveSums[4];
    int t = threadIdx.x;
    int wv = t >> 6, ln = t & 63;
    int base = blockIdx.x * 1024 + t * 4;
    int v[4]; int s = 0;
#pragma unroll
    for (int j = 0; j < 4; ++j) { int i = base + j; v[j] = (i < n) ? indeg[i] : 0; s += v[j]; }
    int x = s;
#pragma unroll
    for (int off = 1; off < 64; off <<= 1) {
        int y = __shfl_up(x, off);
        if (ln >= off) x += y;
    }
    if (ln == 63) waveSums[wv] = x;
    __syncthreads();
    int woff = 0;
    for (int w = 0; w < wv; ++w) woff += waveSums[w];
    int pre = blockOffs[blockIdx.x] + woff + x - s;
#pragma unroll
    for (int j = 0; j < 4; ++j) {
        int i = base + j;
        if (i < n) {
            rowptr[i] = pre;
            cursor[i] = pre;
            dinv[i] = rsqrtf((float)(v[j] + 1));  // +1 self-loop
        }
        pre += v[j];
        if (i == n - 1) rowptr[n] = pre;
    }
}

// scatter also emits per-edge weight wgt[pos] = dinv[src]
__global__ __launch_bounds__(256) void scatter_kernel(const int* __restrict__ esrc,
                                                      const int* __restrict__ edst,
                                                      int* __restrict__ cursor,
                                                      const float* __restrict__ dinv,
                                                      int* __restrict__ col,
                                                      float* __restrict__ wgt, int E) {
    int e = blockIdx.x * 256 + threadIdx.x;
    if (e < E) {
        int d = edst[e];
        int s = esrc[e];
        int pos = atomicAdd(&cursor[d], 1);
        col[pos] = s;
        wgt[pos] = dinv[s];
    }
}

// Both weights: W [k][c] fp32 -> WhT/WlT [c][k] bf16 (transposed)
__global__ __launch_bounds__(256) void split_w2_kernel(const float* __restrict__ W1,
                                                       unsigned short* __restrict__ W1hT,
                                                       unsigned short* __restrict__ W1lT,
                                                       const float* __restrict__ W2,
                                                       unsigned short* __restrict__ W2hT,
                                                       unsigned short* __restrict__ W2lT) {
    int b = blockIdx.x, k = threadIdx.x;
    const float* W = (b < 256) ? W1 : W2;
    unsigned short* Wh = (b < 256) ? W1hT : W2hT;
    unsigned short* Wl = (b < 256) ? W1lT : W2lT;
    int c = b & 255;
    float f = W[k * 256 + c];
    unsigned short h, l; split1(f, h, l);
    Wh[c * 256 + k] = h;
    Wl[c * 256 + k] = l;
}

// x (fp32) -> xh + xl bf16 planes
__global__ __launch_bounds__(256) void split_x_kernel(const float* __restrict__ X,
                                                      unsigned short* __restrict__ Xh,
                                                      unsigned short* __restrict__ Xl,
                                                      int total8) {
    int i = blockIdx.x * 256 + threadIdx.x;
    if (i >= total8) return;
    const float4* p = (const float4*)(X + (size_t)i * 8);
    float4 v0 = p[0], v1 = p[1];
    float f[8] = {v0.x, v0.y, v0.z, v0.w, v1.x, v1.y, v1.z, v1.w};
    u16x8 h, l;
#pragma unroll
    for (int q = 0; q < 8; ++q) { unsigned short hh, ll; split1(f[q], hh, ll); h[q] = hh; l[q] = ll; }
    *(u16x8*)(Xh + (size_t)i * 8) = h;
    *(u16x8*)(Xl + (size_t)i * 8) = l;
}

// ---------------------------------------------------------------------------
// GEMM, BM=64 x BN=256 (full width), BK=32, 256 thr = 4 waves (1x4),
// wave tile 64x64, prefetched staging (loads for k+1 issued before MFMA of k)
// gemm1: A = Ah+Al planes (3 MFMA/frag); gemm2: A exact bf16 (2 MFMA/frag)
// ---------------------------------------------------------------------------
#define APAD 40

__global__ __launch_bounds__(256) void gemm1_k(const unsigned short* __restrict__ Ah_g,
                                               const unsigned short* __restrict__ Al_g,
                                               const unsigned short* __restrict__ BhT,
                                               const unsigned short* __restrict__ BlT,
                                               unsigned short* __restrict__ C, int M) {
    __shared__ unsigned short Ah[64 * APAD];
    __shared__ unsigned short Al[64 * APAD];
    __shared__ unsigned short Bh[256 * APAD];
    __shared__ unsigned short Bl[256 * APAD];

    const int t = threadIdx.x;
    const int row0 = blockIdx.x * 64;
    const int ar = t >> 2, akq = (t & 3) * 8;
    const bool avld = (row0 + ar) < M;
    const int wn = t >> 6, ln = t & 63, lr = ln & 15, lk = (ln >> 4) * 8;

    const unsigned short* aph = Ah_g + (size_t)(row0 + ar) * DIMF + akq;
    const unsigned short* apl = Al_g + (size_t)(row0 + ar) * DIMF + akq;
    const unsigned short* bph = BhT + (size_t)t * DIMF;
    const unsigned short* bpl = BlT + (size_t)t * DIMF;

    f32x4 acc[4][4] = {};
    u16x8 pah = {}, pal = {}, pbh[4], pbl[4];

    // prologue prefetch (k0 = 0)
    if (avld) { pah = *(const u16x8*)(aph); pal = *(const u16x8*)(apl); }
#pragma unroll
    for (int i = 0; i < 4; ++i) {
        pbh[i] = *(const u16x8*)(bph + 8 * i);
        pbl[i] = *(const u16x8*)(bpl + 8 * i);
    }

#pragma unroll
    for (int k0 = 0; k0 < DIMF; k0 += 32) {
        __syncthreads();  // prev frag reads done; prefetch loads drained here
        *(u16x8*)&Ah[ar * APAD + akq] = pah;
        *(u16x8*)&Al[ar * APAD + akq] = pal;
#pragma unroll
        for (int i = 0; i < 4; ++i) {
            *(u16x8*)&Bh[t * APAD + 8 * i] = pbh[i];
            *(u16x8*)&Bl[t * APAD + 8 * i] = pbl[i];
        }
        __syncthreads();

        if (k0 + 32 < DIMF) {  // issue next-tile loads; overlap with MFMA below
            int kn = k0 + 32;
            if (avld) { pah = *(const u16x8*)(aph + kn); pal = *(const u16x8*)(apl + kn); }
#pragma unroll
            for (int i = 0; i < 4; ++i) {
                pbh[i] = *(const u16x8*)(bph + kn + 8 * i);
                pbl[i] = *(const u16x8*)(bpl + kn + 8 * i);
            }
        }

        s16x8 fah[4], fal[4], fbh[4], fbl[4];
#pragma unroll
        for (int fm = 0; fm < 4; ++fm) {
            int rr = fm * 16 + lr;
            fah[fm] = *(const s16x8*)&Ah[rr * APAD + lk];
            fal[fm] = *(const s16x8*)&Al[rr * APAD + lk];
        }
#pragma unroll
        for (int fn = 0; fn < 4; ++fn) {
            int cc = wn * 64 + fn * 16 + lr;
            fbh[fn] = *(const s16x8*)&Bh[cc * APAD + lk];
            fbl[fn] = *(const s16x8*)&Bl[cc * APAD + lk];
        }
#pragma unroll
        for (int fm = 0; fm < 4; ++fm)
#pragma unroll
            for (int fn = 0; fn < 4; ++fn) {
                acc[fm][fn] = __builtin_amdgcn_mfma_f32_16x16x32_bf16(fah[fm], fbh[fn], acc[fm][fn], 0, 0, 0);
                acc[fm][fn] = __builtin_amdgcn_mfma_f32_16x16x32_bf16(fal[fm], fbh[fn], acc[fm][fn], 0, 0, 0);
                acc[fm][fn] = __builtin_amdgcn_mfma_f32_16x16x32_bf16(fah[fm], fbl[fn], acc[fm][fn], 0, 0, 0);
            }
    }

#pragma unroll
    for (int fm = 0; fm < 4; ++fm)
#pragma unroll
        for (int fn = 0; fn < 4; ++fn)
#pragma unroll
            for (int q = 0; q < 4; ++q) {
                int row = row0 + fm * 16 + (ln >> 4) * 4 + q;
                int colc = wn * 64 + fn * 16 + lr;
                if (row < M) C[(size_t)row * DIMF + colc] = f2bf(acc[fm][fn][q]);
            }
}

__global__ __launch_bounds__(256) void gemm2_k(const unsigned short* __restrict__ Ah_g,
                                               const unsigned short* __restrict__ BhT,
                                               const unsigned short* __restrict__ BlT,
                                               unsigned short* __restrict__ C, int M) {
    __shared__ unsigned short Ah[64 * APAD];
    __shared__ unsigned short Bh[256 * APAD];
    __shared__ unsigned short Bl[256 * APAD];

    const int t = threadIdx.x;
    const int row0 = blockIdx.x * 64;
    const int ar = t >> 2, akq = (t & 3) * 8;
    const bool avld = (row0 + ar) < M;
    const int wn = t >> 6, ln = t & 63, lr = ln & 15, lk = (ln >> 4) * 8;

    const unsigned short* aph = Ah_g + (size_t)(row0 + ar) * DIMF + akq;
    const unsigned short* bph = BhT + (size_t)t * DIMF;
    const unsigned short* bpl = BlT + (size_t)t * DIMF;

    f32x4 acc[4][4] = {};
    u16x8 pah = {}, pbh[4], pbl[4];

    if (avld) pah = *(const u16x8*)(aph);
#pragma unroll
    for (int i = 0; i < 4; ++i) {
        pbh[i] = *(const u16x8*)(bph + 8 * i);
        pbl[i] = *(const u16x8*)(bpl + 8 * i);
    }

#pragma unroll
    for (int k0 = 0; k0 < DIMF; k0 += 32) {
        __syncthreads();
        *(u16x8*)&Ah[ar * APAD + akq] = pah;
#pragma unroll
        for (int i = 0; i < 4; ++i) {
            *(u16x8*)&Bh[t * APAD + 8 * i] = pbh[i];
            *(u16x8*)&Bl[t * APAD + 8 * i] = pbl[i];
        }
        __syncthreads();

        if (k0 + 32 < DIMF) {
            int kn = k0 + 32;
            if (avld) pah = *(const u16x8*)(aph + kn);
#pragma unroll
            for (int i = 0; i < 4; ++i) {
                pbh[i] = *(const u16x8*)(bph + kn + 8 * i);
                pbl[i] = *(const u16x8*)(bpl + kn + 8 * i);
            }
        }

        s16x8 fah[4], fbh[4], fbl[4];
#pragma unroll
        for (int fm = 0; fm < 4; ++fm) {
            int rr = fm * 16 + lr;
            fah[fm] = *(const s16x8*)&Ah[rr * APAD + lk];
        }
#pragma unroll
        for (int fn = 0; fn < 4; ++fn) {
            int cc = wn * 64 + fn * 16 + lr;
            fbh[fn] = *(const s16x8*)&Bh[cc * APAD + lk];
            fbl[fn] = *(const s16x8*)&Bl[cc * APAD + lk];
        }
#pragma unroll
        for (int fm = 0; fm < 4; ++fm)
#pragma unroll
            for (int fn = 0; fn < 4; ++fn) {
                acc[fm][fn] = __builtin_amdgcn_mfma_f32_16x16x32_bf16(fah[fm], fbh[fn], acc[fm][fn], 0, 0, 0);
                acc[fm][fn] = __builtin_amdgcn_mfma_f32_16x16x32_bf16(fah[fm], fbl[fn], acc[fm][fn], 0, 0, 0);
            }
    }

#pragma unroll
    for (int fm = 0; fm < 4; ++fm)
#pragma unroll
        for (int fn = 0; fn < 4; ++fn)
#pragma unroll
            for (int q = 0; q < 4; ++q) {
                int row = row0 + fm * 16 + (ln >> 4) * 4 + q;
                int colc = wn * 64 + fn * 16 + lr;
                if (row < M) C[(size_t)row * DIMF + colc] = f2bf(acc[fm][fn][q]);
            }
}

// ---------------------------------------------------------------------------
// Aggregation: wave/node; half-wave per edge row (16B/lane); 4 gathers in flight
// col+wgt are sequential streams (wgt[e] = dinv[src[e]])
// ---------------------------------------------------------------------------
#define ACC8(a, h, w)                                   \
    do {                                                \
        _Pragma("unroll")                               \
        for (int q = 0; q < 8; ++q)                     \
            a[q] = fmaf(bf2f((h)[q]), (w), a[q]);       \
    } while (0)

__device__ __forceinline__ void agg_core(const unsigned short* __restrict__ G,
                                         const int* __restrict__ rowptr,
                                         const int* __restrict__ col,
                                         const float* __restrict__ wgt,
                                         int node, int ln, int half, int sub,
                                         float di, float (&a)[8]) {
    if (half == 0) {
        u16x8 h = *(const u16x8*)&G[(size_t)node * DIMF + sub * 8];
        ACC8(a, h, di);
    }
    int e0 = rowptr[node], e1 = rowptr[node + 1];
    for (int base = e0; base < e1; base += 64) {
        int cnt = min(64, e1 - base);
        int idx = 0; float dv = 0.f;
        if (ln < cnt) { idx = col[base + ln]; dv = wgt[base + ln]; }
        int j = 0;
        for (; j + 8 <= cnt; j += 8) {
            int s0 = __shfl(idx, j + half),     s1 = __shfl(idx, j + 2 + half);
            int s2 = __shfl(idx, j + 4 + half), s3 = __shfl(idx, j + 6 + half);
            float w0 = __shfl(dv, j + half),     w1 = __shfl(dv, j + 2 + half);
            float w2 = __shfl(dv, j + 4 + half), w3 = __shfl(dv, j + 6 + half);
            u16x8 h0 = *(const u16x8*)&G[(size_t)s0 * DIMF + sub * 8];
            u16x8 h1 = *(const u16x8*)&G[(size_t)s1 * DIMF + sub * 8];
            u16x8 h2 = *(const u16x8*)&G[(size_t)s2 * DIMF + sub * 8];
            u16x8 h3 = *(const u16x8*)&G[(size_t)s3 * DIMF + sub * 8];
            ACC8(a, h0, w0); ACC8(a, h1, w1); ACC8(a, h2, w2); ACC8(a, h3, w3);
        }
        for (; j + 2 <= cnt; j += 2) {
            int s = __shfl(idx, j + half);
            float wv = __shfl(dv, j + half);
            u16x8 h = *(const u16x8*)&G[(size_t)s * DIMF + sub * 8];
            ACC8(a, h, wv);
        }
        if (j < cnt) {
            int s = __shfl(idx, j);
            float wv = __shfl(dv, j);
            if (half == 0) {
                u16x8 h = *(const u16x8*)&G[(size_t)s * DIMF + sub * 8];
                ACC8(a, h, wv);
            }
        }
    }
#pragma unroll
    for (int q = 0; q < 8; ++q) a[q] += __shfl_xor(a[q], 32);
}

__global__ __launch_bounds__(256) void agg_bf16(const unsigned short* __restrict__ G,
                                                const int* __restrict__ rowptr,
                                                const int* __restrict__ col,
                                                const float* __restrict__ wgt,
                                                const float* __restrict__ dinv,
                                                const float* __restrict__ bias,
                                                unsigned short* __restrict__ out, int N) {
    int wave = threadIdx.x >> 6;
    int ln = threadIdx.x & 63;
    int half = ln >> 5, sub = ln & 31;
    int node = blockIdx.x * 4 + wave;
    if (node >= N) return;

    float di = dinv[node];
    float a[8] = {};
    agg_core(G, rowptr, col, wgt, node, ln, half, sub, di, a);

    if (half == 0) {
        float4 b0 = *(const float4*)&bias[sub * 8];
        float4 b1 = *(const float4*)&bias[sub * 8 + 4];
        float bb[8] = {b0.x, b0.y, b0.z, b0.w, b1.x, b1.y, b1.z, b1.w};
        u16x8 o;
#pragma unroll
        for (int q = 0; q < 8; ++q) o[q] = f2bf(fmaxf(fmaf(a[q], di, bb[q]), 0.f));
        *(u16x8*)&out[(size_t)node * DIMF + sub * 8] = o;
    }
}

__global__ __launch_bounds__(256) void agg_fc_bf16(const unsigned short* __restrict__ G,
                                                   const int* __restrict__ rowptr,
                                                   const int* __restrict__ col,
                                                   const float* __restrict__ wgt,
                                                   const float* __restrict__ dinv,
                                                   const float* __restrict__ bias,
                                                   const float* __restrict__ Wfc,
                                                   const float* __restrict__ bfc,
                                                   float* __restrict__ out, int N) {
    int wave = threadIdx.x >> 6;
    int ln = threadIdx.x & 63;
    int half = ln >> 5, sub = ln & 31;
    int node = blockIdx.x * 4 + wave;
    if (node >= N) return;

    float di = dinv[node];
    float a[8] = {};
    agg_core(G, rowptr, col, wgt, node, ln, half, sub, di, a);

    float4 b0 = *(const float4*)&bias[sub * 8];
    float4 b1 = *(const float4*)&bias[sub * 8 + 4];
    float bb[8] = {b0.x, b0.y, b0.z, b0.w, b1.x, b1.y, b1.z, b1.w};
#pragma unroll
    for (int q = 0; q < 8; ++q) a[q] = fmaxf(fmaf(a[q], di, bb[q]), 0.f);

    float4 wA = *(const float4*)&Wfc[sub * 16];
    float4 wB = *(const float4*)&Wfc[sub * 16 + 4];
    float4 wC = *(const float4*)&Wfc[sub * 16 + 8];
    float4 wD = *(const float4*)&Wfc[sub * 16 + 12];
    float s0 = a[0] * wA.x + a[1] * wA.z + a[2] * wB.x + a[3] * wB.z
             + a[4] * wC.x + a[5] * wC.z + a[6] * wD.x + a[7] * wD.z;
    float s1 = a[0] * wA.y + a[1] * wA.w + a[2] * wB.y + a[3] * wB.w
             + a[4] * wC.y + a[5] * wC.w + a[6] * wD.y + a[7] * wD.w;
#pragma unroll
    for (int off = 16; off > 0; off >>= 1) {
        s0 += __shfl_xor(s0, off);
        s1 += __shfl_xor(s1, off);
    }
    if (ln == 0) {
        s0 += bfc[0];
        s1 += bfc[1];
        float m = fmaxf(s0, s1);
        float lse = m + logf(__expf(s0 - m) + __expf(s1 - m));
        out[(size_t)node * 2 + 0] = s0 - lse;
        out[(size_t)node * 2 + 1] = s1 - lse;
    }
}

// ---------------------------------------------------------------------------
// Host launcher
// ---------------------------------------------------------------------------
static inline size_t align256(size_t x) { return (x + 255) & ~(size_t)255; }

extern "C" void kernel_launch(void* const* d_in, const int* in_sizes, int n_in,
                              void* d_out, int out_size, void* d_ws, size_t ws_size,
                              hipStream_t stream) {
    const float* x   = (const float*)d_in[0];
    const int* eidx  = (const int*)d_in[1];
    const float* W1  = (const float*)d_in[2];
    const float* b1  = (const float*)d_in[3];
    const float* W2  = (const float*)d_in[4];
    const float* b2  = (const float*)d_in[5];
    const float* Wfc = (const float*)d_in[6];
    const float* bfc = (const float*)d_in[7];
    float* out = (float*)d_out;

    const int N = in_sizes[0] / DIMF;     // 50000
    const int E = in_sizes[1] / 2;        // 800000
    const int* esrc = eidx;
    const int* edst = eidx + E;

    // workspace layout
    char* w = (char*)d_ws;
    size_t off = 0;
    int*   indeg  = (int*)(w + off);   off = align256(off + (size_t)N * 4);
    float* dinv   = (float*)(w + off); off = align256(off + (size_t)N * 4);
    int*   rowptr = (int*)(w + off);   off = align256(off + (size_t)(N + 1) * 4);
    int*   cursor = (int*)(w + off);   off = align256(off + (size_t)N * 4);
    int*   bsums  = (int*)(w + off);   off = align256(off + (size_t)1024 * 4);
    int*   col    = (int*)(w + off);   off = align256(off + (size_t)E * 4);
    float* wgt    = (float*)(w + off); off = align256(off + (size_t)E * 4);
    unsigned short* xh   = (unsigned short*)(w + off); off = align256(off + (size_t)N * DIMF * 2);
    unsigned short* xl   = (unsigned short*)(w + off); off = align256(off + (size_t)N * DIMF * 2);
    unsigned short* bufA = (unsigned short*)(w + off); off = align256(off + (size_t)N * DIMF * 2);
    unsigned short* bufB = (unsigned short*)(w + off); off = align256(off + (size_t)N * DIMF * 2);
    unsigned short* w1h  = (unsigned short*)(w + off); off = align256(off + (size_t)65536 * 2);
    unsigned short* w1l  = (unsigned short*)(w + off); off = align256(off + (size_t)65536 * 2);
    unsigned short* w2h  = (unsigned short*)(w + off); off = align256(off + (size_t)65536 * 2);
    unsigned short* w2l  = (unsigned short*)(w + off); off = align256(off + (size_t)65536 * 2);
    (void)ws_size;

    int gE = (E + 255) / 256;
    int gNode = (N + 3) / 4;
    int nb1024 = (N + 1023) / 1024;
    int total8 = N * DIMF / 8;

    // 1) CSR build + pre-splits
    hipMemsetAsync(indeg, 0, (size_t)N * 4, stream);
    hist_kernel<<<gE, 256, 0, stream>>>(edst, indeg, E);
    scan_partial<<<nb1024, 256, 0, stream>>>(indeg, bsums, N);
    scan_sums<<<1, 64, 0, stream>>>(bsums, nb1024);
    scan_final<<<nb1024, 256, 0, stream>>>(indeg, bsums, rowptr, cursor, dinv, N);
    scatter_kernel<<<gE, 256, 0, stream>>>(esrc, edst, cursor, dinv, col, wgt, E);
    split_w2_kernel<<<512, 256, 0, stream>>>(W1, w1h, w1l, W2, w2h, w2l);
    split_x_kernel<<<(total8 + 255) / 256, 256, 0, stream>>>(x, xh, xl, total8);

    // 2) conv1: bufA = bf16(x @ W1); bufB = bf16(relu(agg(bufA) + b1))
    int gGemm = (N + 63) / 64;
    gemm1_k<<<gGemm, 256, 0, stream>>>(xh, xl, w1h, w1l, bufA, N);
    agg_bf16<<<gNode, 256, 0, stream>>>(bufA, rowptr, col, wgt, dinv, b1, bufB, N);

    // 3) conv2: bufA = bf16(bufB @ W2)
    gemm2_k<<<gGemm, 256, 0, stream>>>(bufB, w2h, w2l, bufA, N);

    // 4) agg2 + FC + log_softmax fused
    agg_fc_bf16<<<gNode, 256, 0, stream>>>(bufA, rowptr, col, wgt, dinv, b2, Wfc, bfc, out, N);
}

// Round 7
// 283.730 us; speedup vs baseline: 1.1561x; 1.1561x over previous
//
#include <hip/hip_runtime.h>
#include <hip/hip_bf16.h>
#include <math.h>

#define DIMF 256   // feature dim (d = h = 256)

typedef __attribute__((ext_vector_type(8))) short s16x8;
typedef __attribute__((ext_vector_type(4))) float f32x4;
typedef __attribute__((ext_vector_type(8))) unsigned short u16x8;

__device__ __forceinline__ float bf2f(unsigned short u) {
    return __uint_as_float(((unsigned)u) << 16);
}
__device__ __forceinline__ unsigned short f2bf(float f) {  // RNE
    unsigned u = __float_as_uint(f);
    u += 0x7FFFu + ((u >> 16) & 1u);
    return (unsigned short)(u >> 16);
}
__device__ __forceinline__ void split1(float f, unsigned short& h, unsigned short& l) {
    unsigned u = __float_as_uint(f);
    h = (unsigned short)(u >> 16);
    float r = f - __uint_as_float(u & 0xFFFF0000u);
    l = (unsigned short)(__float_as_uint(r) >> 16);
}

// ---------------------------------------------------------------------------
// CSR build
// ---------------------------------------------------------------------------
__global__ __launch_bounds__(256) void hist_kernel(const int* __restrict__ dst,
                                                   int* __restrict__ indeg, int E) {
    int e = blockIdx.x * 256 + threadIdx.x;
    if (e < E) atomicAdd(&indeg[dst[e]], 1);
}

__global__ __launch_bounds__(256) void scan_partial(const int* __restrict__ indeg,
                                                    int* __restrict__ blockSums, int n) {
    int t = threadIdx.x;
    int base = blockIdx.x * 1024 + t * 4;
    int s = 0;
#pragma unroll
    for (int j = 0; j < 4; ++j) { int i = base + j; if (i < n) s += indeg[i]; }
#pragma unroll
    for (int off = 32; off > 0; off >>= 1) s += __shfl_down(s, off);
    __shared__ int sm[4];
    if ((t & 63) == 0) sm[t >> 6] = s;
    __syncthreads();
    if (t == 0) blockSums[blockIdx.x] = sm[0] + sm[1] + sm[2] + sm[3];
}

__global__ __launch_bounds__(64) void scan_sums(int* __restrict__ blockSums, int nb) {
    int t = threadIdx.x;
    int carry = 0;
    for (int base = 0; base < nb; base += 64) {
        int i = base + t;
        int v = (i < nb) ? blockSums[i] : 0;
        int x = v;
#pragma unroll
        for (int off = 1; off < 64; off <<= 1) {
            int y = __shfl_up(x, off);
            if (t >= off) x += y;
        }
        if (i < nb) blockSums[i] = carry + x - v;  // exclusive
        carry += __shfl(x, 63);
    }
}

// scan_final also emits dinv (folded dinv_kernel)
__global__ __launch_bounds__(256) void scan_final(const int* __restrict__ indeg,
                                                  const int* __restrict__ blockOffs,
                                                  int* __restrict__ rowptr,
                                                  int* __restrict__ cursor,
                                                  float* __restrict__ dinv, int n) {
    __shared__ int waveSums[4];
    int t = threadIdx.x;
    int wv = t >> 6, ln = t & 63;
    int base = blockIdx.x * 1024 + t * 4;
    int v[4]; int s = 0;
#pragma unroll
    for (int j = 0; j < 4; ++j) { int i = base + j; v[j] = (i < n) ? indeg[i] : 0; s += v[j]; }
    int x = s;
#pragma unroll
    for (int off = 1; off < 64; off <<= 1) {
        int y = __shfl_up(x, off);
        if (ln >= off) x += y;
    }
    if (ln == 63) waveSums[wv] = x;
    __syncthreads();
    int woff = 0;
    for (int w = 0; w < wv; ++w) woff += waveSums[w];
    int pre = blockOffs[blockIdx.x] + woff + x - s;
#pragma unroll
    for (int j = 0; j < 4; ++j) {
        int i = base + j;
        if (i < n) {
            rowptr[i] = pre;
            cursor[i] = pre;
            dinv[i] = rsqrtf((float)(v[j] + 1));  // +1 self-loop
        }
        pre += v[j];
        if (i == n - 1) rowptr[n] = pre;
    }
}

// col-only scatter (wgt stream proved cost-neutral in agg, +20us in scatter)
__global__ __launch_bounds__(256) void scatter_kernel(const int* __restrict__ esrc,
                                                      const int* __restrict__ edst,
                                                      int* __restrict__ cursor,
                                                      int* __restrict__ col, int E) {
    int e = blockIdx.x * 256 + threadIdx.x;
    if (e < E) {
        int d = edst[e];
        int pos = atomicAdd(&cursor[d], 1);
        col[pos] = esrc[e];
    }
}

// Both weights: W [k][c] fp32 -> WhT/WlT [c][k] bf16 (transposed)
__global__ __launch_bounds__(256) void split_w2_kernel(const float* __restrict__ W1,
                                                       unsigned short* __restrict__ W1hT,
                                                       unsigned short* __restrict__ W1lT,
                                                       const float* __restrict__ W2,
                                                       unsigned short* __restrict__ W2hT,
                                                       unsigned short* __restrict__ W2lT) {
    int b = blockIdx.x, k = threadIdx.x;
    const float* W = (b < 256) ? W1 : W2;
    unsigned short* Wh = (b < 256) ? W1hT : W2hT;
    unsigned short* Wl = (b < 256) ? W1lT : W2lT;
    int c = b & 255;
    float f = W[k * 256 + c];
    unsigned short h, l; split1(f, h, l);
    Wh[c * 256 + k] = h;
    Wl[c * 256 + k] = l;
}

// ---------------------------------------------------------------------------
// GEMM 1: A fp32 (in-kernel hi/lo split) x B pre-split -> C bf16
// BM=BN=128, BK=32; 256 thr = 4 waves (2x2), wave tile 64x64; 3 MFMA/frag
// ---------------------------------------------------------------------------
#define APAD 40

__global__ __launch_bounds__(256) void gemm_splitA(const float* __restrict__ A,
                                                   const unsigned short* __restrict__ BhT,
                                                   const unsigned short* __restrict__ BlT,
                                                   unsigned short* __restrict__ C, int M) {
    __shared__ unsigned short Ah[128 * APAD];
    __shared__ unsigned short Al[128 * APAD];
    __shared__ unsigned short Bh[128 * APAD];
    __shared__ unsigned short Bl[128 * APAD];

    const int t = threadIdx.x;
    const int row0 = blockIdx.x * 128;
    const int col0 = blockIdx.y * 128;
    const int r = t >> 1;
    const int kh = (t & 1) * 16;
    const bool av = (row0 + r) < M;

    const int wv = t >> 6, wm = wv >> 1, wn = wv & 1;
    const int ln = t & 63, lr = ln & 15, lk = (ln >> 4) * 8;

    f32x4 acc[4][4] = {};

    const float* ap = A + (size_t)(row0 + r) * DIMF + kh;
    const unsigned short* bph = BhT + (size_t)(col0 + r) * DIMF + kh;
    const unsigned short* bpl = BlT + (size_t)(col0 + r) * DIMF + kh;

    for (int k0 = 0; k0 < DIMF; k0 += 32) {
        float4 a4[4] = {};
        if (av) {
#pragma unroll
            for (int i = 0; i < 4; ++i) a4[i] = *(const float4*)(ap + k0 + 4 * i);
        }
        u16x8 b0 = *(const u16x8*)(bph + k0), b1 = *(const u16x8*)(bph + k0 + 8);
        u16x8 d0 = *(const u16x8*)(bpl + k0), d1 = *(const u16x8*)(bpl + k0 + 8);

        __syncthreads();
        {
            float f[16] = {a4[0].x, a4[0].y, a4[0].z, a4[0].w,
                           a4[1].x, a4[1].y, a4[1].z, a4[1].w,
                           a4[2].x, a4[2].y, a4[2].z, a4[2].w,
                           a4[3].x, a4[3].y, a4[3].z, a4[3].w};
            u16x8 h0, h1, l0, l1;
#pragma unroll
            for (int q = 0; q < 8; ++q) { unsigned short hh, ll; split1(f[q], hh, ll); h0[q] = hh; l0[q] = ll; }
#pragma unroll
            for (int q = 0; q < 8; ++q) { unsigned short hh, ll; split1(f[8 + q], hh, ll); h1[q] = hh; l1[q] = ll; }
            *(u16x8*)&Ah[r * APAD + kh] = h0; *(u16x8*)&Ah[r * APAD + kh + 8] = h1;
            *(u16x8*)&Al[r * APAD + kh] = l0; *(u16x8*)&Al[r * APAD + kh + 8] = l1;
        }
        *(u16x8*)&Bh[r * APAD + kh] = b0; *(u16x8*)&Bh[r * APAD + kh + 8] = b1;
        *(u16x8*)&Bl[r * APAD + kh] = d0; *(u16x8*)&Bl[r * APAD + kh + 8] = d1;
        __syncthreads();

        s16x8 fah[4], fal[4], fbh[4], fbl[4];
#pragma unroll
        for (int fm = 0; fm < 4; ++fm) {
            int rr = wm * 64 + fm * 16 + lr;
            fah[fm] = *(const s16x8*)&Ah[rr * APAD + lk];
            fal[fm] = *(const s16x8*)&Al[rr * APAD + lk];
        }
#pragma unroll
        for (int fn = 0; fn < 4; ++fn) {
            int cc = wn * 64 + fn * 16 + lr;
            fbh[fn] = *(const s16x8*)&Bh[cc * APAD + lk];
            fbl[fn] = *(const s16x8*)&Bl[cc * APAD + lk];
        }
#pragma unroll
        for (int fm = 0; fm < 4; ++fm)
#pragma unroll
            for (int fn = 0; fn < 4; ++fn) {
                acc[fm][fn] = __builtin_amdgcn_mfma_f32_16x16x32_bf16(fah[fm], fbh[fn], acc[fm][fn], 0, 0, 0);
                acc[fm][fn] = __builtin_amdgcn_mfma_f32_16x16x32_bf16(fal[fm], fbh[fn], acc[fm][fn], 0, 0, 0);
                acc[fm][fn] = __builtin_amdgcn_mfma_f32_16x16x32_bf16(fah[fm], fbl[fn], acc[fm][fn], 0, 0, 0);
            }
    }

#pragma unroll
    for (int fm = 0; fm < 4; ++fm)
#pragma unroll
        for (int fn = 0; fn < 4; ++fn)
#pragma unroll
            for (int q = 0; q < 4; ++q) {
                int row = row0 + wm * 64 + fm * 16 + (ln >> 4) * 4 + q;
                int colc = col0 + wn * 64 + fn * 16 + lr;
                if (row < M) C[(size_t)row * DIMF + colc] = f2bf(acc[fm][fn][q]);
            }
}

// GEMM 2 (exact bf16 A): 2 MFMA/frag
__global__ __launch_bounds__(256) void gemm_exact(const unsigned short* __restrict__ Ah_g,
                                                  const unsigned short* __restrict__ BhT,
                                                  const unsigned short* __restrict__ BlT,
                                                  unsigned short* __restrict__ C, int M) {
    __shared__ unsigned short Ah[128 * APAD];
    __shared__ unsigned short Bh[128 * APAD];
    __shared__ unsigned short Bl[128 * APAD];

    const int t = threadIdx.x;
    const int row0 = blockIdx.x * 128;
    const int col0 = blockIdx.y * 128;
    const int r = t >> 1;
    const int kh = (t & 1) * 16;
    const bool av = (row0 + r) < M;

    const int wv = t >> 6, wm = wv >> 1, wn = wv & 1;
    const int ln = t & 63, lr = ln & 15, lk = (ln >> 4) * 8;

    f32x4 acc[4][4] = {};

    const unsigned short* aph = Ah_g + (size_t)(row0 + r) * DIMF + kh;
    const unsigned short* bph = BhT + (size_t)(col0 + r) * DIMF + kh;
    const unsigned short* bpl = BlT + (size_t)(col0 + r) * DIMF + kh;

    for (int k0 = 0; k0 < DIMF; k0 += 32) {
        u16x8 a0 = {}, a1 = {};
        if (av) {
            a0 = *(const u16x8*)(aph + k0); a1 = *(const u16x8*)(aph + k0 + 8);
        }
        u16x8 b0 = *(const u16x8*)(bph + k0), b1 = *(const u16x8*)(bph + k0 + 8);
        u16x8 d0 = *(const u16x8*)(bpl + k0), d1 = *(const u16x8*)(bpl + k0 + 8);

        __syncthreads();
        *(u16x8*)&Ah[r * APAD + kh] = a0; *(u16x8*)&Ah[r * APAD + kh + 8] = a1;
        *(u16x8*)&Bh[r * APAD + kh] = b0; *(u16x8*)&Bh[r * APAD + kh + 8] = b1;
        *(u16x8*)&Bl[r * APAD + kh] = d0; *(u16x8*)&Bl[r * APAD + kh + 8] = d1;
        __syncthreads();

        s16x8 fah[4], fbh[4], fbl[4];
#pragma unroll
        for (int fm = 0; fm < 4; ++fm) {
            int rr = wm * 64 + fm * 16 + lr;
            fah[fm] = *(const s16x8*)&Ah[rr * APAD + lk];
        }
#pragma unroll
        for (int fn = 0; fn < 4; ++fn) {
            int cc = wn * 64 + fn * 16 + lr;
            fbh[fn] = *(const s16x8*)&Bh[cc * APAD + lk];
            fbl[fn] = *(const s16x8*)&Bl[cc * APAD + lk];
        }
#pragma unroll
        for (int fm = 0; fm < 4; ++fm)
#pragma unroll
            for (int fn = 0; fn < 4; ++fn) {
                acc[fm][fn] = __builtin_amdgcn_mfma_f32_16x16x32_bf16(fah[fm], fbh[fn], acc[fm][fn], 0, 0, 0);
                acc[fm][fn] = __builtin_amdgcn_mfma_f32_16x16x32_bf16(fah[fm], fbl[fn], acc[fm][fn], 0, 0, 0);
            }
    }

#pragma unroll
    for (int fm = 0; fm < 4; ++fm)
#pragma unroll
        for (int fn = 0; fn < 4; ++fn)
#pragma unroll
            for (int q = 0; q < 4; ++q) {
                int row = row0 + wm * 64 + fm * 16 + (ln >> 4) * 4 + q;
                int colc = col0 + wn * 64 + fn * 16 + lr;
                if (row < M) C[(size_t)row * DIMF + colc] = f2bf(acc[fm][fn][q]);
            }
}

// ---------------------------------------------------------------------------
// Aggregation: wave/node; half-wave per edge row (16B/lane); 4 gathers in flight
// ---------------------------------------------------------------------------
#define ACC8(a, h, w)                                   \
    do {                                                \
        _Pragma("unroll")                               \
        for (int q = 0; q < 8; ++q)                     \
            a[q] = fmaf(bf2f((h)[q]), (w), a[q]);       \
    } while (0)

__device__ __forceinline__ void agg_core(const unsigned short* __restrict__ G,
                                         const int* __restrict__ rowptr,
                                         const int* __restrict__ col,
                                         const float* __restrict__ dinv,
                                         int node, int ln, int half, int sub,
                                         float di, float (&a)[8]) {
    if (half == 0) {
        u16x8 h = *(const u16x8*)&G[(size_t)node * DIMF + sub * 8];
        ACC8(a, h, di);
    }
    int e0 = rowptr[node], e1 = rowptr[node + 1];
    for (int base = e0; base < e1; base += 64) {
        int cnt = min(64, e1 - base);
        int idx = 0; float dv = 0.f;
        if (ln < cnt) { idx = col[base + ln]; dv = dinv[idx]; }
        int j = 0;
        for (; j + 8 <= cnt; j += 8) {
            int s0 = __shfl(idx, j + half),     s1 = __shfl(idx, j + 2 + half);
            int s2 = __shfl(idx, j + 4 + half), s3 = __shfl(idx, j + 6 + half);
            float w0 = __shfl(dv, j + half),     w1 = __shfl(dv, j + 2 + half);
            float w2 = __shfl(dv, j + 4 + half), w3 = __shfl(dv, j + 6 + half);
            u16x8 h0 = *(const u16x8*)&G[(size_t)s0 * DIMF + sub * 8];
            u16x8 h1 = *(const u16x8*)&G[(size_t)s1 * DIMF + sub * 8];
            u16x8 h2 = *(const u16x8*)&G[(size_t)s2 * DIMF + sub * 8];
            u16x8 h3 = *(const u16x8*)&G[(size_t)s3 * DIMF + sub * 8];
            ACC8(a, h0, w0); ACC8(a, h1, w1); ACC8(a, h2, w2); ACC8(a, h3, w3);
        }
        for (; j + 2 <= cnt; j += 2) {
            int s = __shfl(idx, j + half);
            float wv = __shfl(dv, j + half);
            u16x8 h = *(const u16x8*)&G[(size_t)s * DIMF + sub * 8];
            ACC8(a, h, wv);
        }
        if (j < cnt) {
            int s = __shfl(idx, j);
            float wv = __shfl(dv, j);
            if (half == 0) {
                u16x8 h = *(const u16x8*)&G[(size_t)s * DIMF + sub * 8];
                ACC8(a, h, wv);
            }
        }
    }
#pragma unroll
    for (int q = 0; q < 8; ++q) a[q] += __shfl_xor(a[q], 32);
}

__global__ __launch_bounds__(256) void agg_bf16(const unsigned short* __restrict__ G,
                                                const int* __restrict__ rowptr,
                                                const int* __restrict__ col,
                                                const float* __restrict__ dinv,
                                                const float* __restrict__ bias,
                                                unsigned short* __restrict__ out, int N) {
    int wave = threadIdx.x >> 6;
    int ln = threadIdx.x & 63;
    int half = ln >> 5, sub = ln & 31;
    int node = blockIdx.x * 4 + wave;
    if (node >= N) return;

    float di = dinv[node];
    float a[8] = {};
    agg_core(G, rowptr, col, dinv, node, ln, half, sub, di, a);

    if (half == 0) {
        float4 b0 = *(const float4*)&bias[sub * 8];
        float4 b1 = *(const float4*)&bias[sub * 8 + 4];
        float bb[8] = {b0.x, b0.y, b0.z, b0.w, b1.x, b1.y, b1.z, b1.w};
        u16x8 o;
#pragma unroll
        for (int q = 0; q < 8; ++q) o[q] = f2bf(fmaxf(fmaf(a[q], di, bb[q]), 0.f));
        *(u16x8*)&out[(size_t)node * DIMF + sub * 8] = o;
    }
}

__global__ __launch_bounds__(256) void agg_fc_bf16(const unsigned short* __restrict__ G,
                                                   const int* __restrict__ rowptr,
                                                   const int* __restrict__ col,
                                                   const float* __restrict__ dinv,
                                                   const float* __restrict__ bias,
                                                   const float* __restrict__ Wfc,
                                                   const float* __restrict__ bfc,
                                                   float* __restrict__ out, int N) {
    int wave = threadIdx.x >> 6;
    int ln = threadIdx.x & 63;
    int half = ln >> 5, sub = ln & 31;
    int node = blockIdx.x * 4 + wave;
    if (node >= N) return;

    float di = dinv[node];
    float a[8] = {};
    agg_core(G, rowptr, col, dinv, node, ln, half, sub, di, a);

    float4 b0 = *(const float4*)&bias[sub * 8];
    float4 b1 = *(const float4*)&bias[sub * 8 + 4];
    float bb[8] = {b0.x, b0.y, b0.z, b0.w, b1.x, b1.y, b1.z, b1.w};
#pragma unroll
    for (int q = 0; q < 8; ++q) a[q] = fmaxf(fmaf(a[q], di, bb[q]), 0.f);

    float4 wA = *(const float4*)&Wfc[sub * 16];
    float4 wB = *(const float4*)&Wfc[sub * 16 + 4];
    float4 wC = *(const float4*)&Wfc[sub * 16 + 8];
    float4 wD = *(const float4*)&Wfc[sub * 16 + 12];
    float s0 = a[0] * wA.x + a[1] * wA.z + a[2] * wB.x + a[3] * wB.z
             + a[4] * wC.x + a[5] * wC.z + a[6] * wD.x + a[7] * wD.z;
    float s1 = a[0] * wA.y + a[1] * wA.w + a[2] * wB.y + a[3] * wB.w
             + a[4] * wC.y + a[5] * wC.w + a[6] * wD.y + a[7] * wD.w;
#pragma unroll
    for (int off = 16; off > 0; off >>= 1) {
        s0 += __shfl_xor(s0, off);
        s1 += __shfl_xor(s1, off);
    }
    if (ln == 0) {
        s0 += bfc[0];
        s1 += bfc[1];
        float m = fmaxf(s0, s1);
        float lse = m + logf(__expf(s0 - m) + __expf(s1 - m));
        out[(size_t)node * 2 + 0] = s0 - lse;
        out[(size_t)node * 2 + 1] = s1 - lse;
    }
}

// ---------------------------------------------------------------------------
// Host launcher
// ---------------------------------------------------------------------------
static inline size_t align256(size_t x) { return (x + 255) & ~(size_t)255; }

extern "C" void kernel_launch(void* const* d_in, const int* in_sizes, int n_in,
                              void* d_out, int out_size, void* d_ws, size_t ws_size,
                              hipStream_t stream) {
    const float* x   = (const float*)d_in[0];
    const int* eidx  = (const int*)d_in[1];
    const float* W1  = (const float*)d_in[2];
    const float* b1  = (const float*)d_in[3];
    const float* W2  = (const float*)d_in[4];
    const float* b2  = (const float*)d_in[5];
    const float* Wfc = (const float*)d_in[6];
    const float* bfc = (const float*)d_in[7];
    float* out = (float*)d_out;

    const int N = in_sizes[0] / DIMF;     // 50000
    const int E = in_sizes[1] / 2;        // 800000
    const int* esrc = eidx;
    const int* edst = eidx + E;

    // workspace layout
    char* w = (char*)d_ws;
    size_t off = 0;
    int*   indeg  = (int*)(w + off);   off = align256(off + (size_t)N * 4);
    float* dinv   = (float*)(w + off); off = align256(off + (size_t)N * 4);
    int*   rowptr = (int*)(w + off);   off = align256(off + (size_t)(N + 1) * 4);
    int*   cursor = (int*)(w + off);   off = align256(off + (size_t)N * 4);
    int*   bsums  = (int*)(w + off);   off = align256(off + (size_t)1024 * 4);
    int*   col    = (int*)(w + off);   off = align256(off + (size_t)E * 4);
    unsigned short* bufA = (unsigned short*)(w + off); off = align256(off + (size_t)N * DIMF * 2);
    unsigned short* bufB = (unsigned short*)(w + off); off = align256(off + (size_t)N * DIMF * 2);
    unsigned short* w1h  = (unsigned short*)(w + off); off = align256(off + (size_t)65536 * 2);
    unsigned short* w1l  = (unsigned short*)(w + off); off = align256(off + (size_t)65536 * 2);
    unsigned short* w2h  = (unsigned short*)(w + off); off = align256(off + (size_t)65536 * 2);
    unsigned short* w2l  = (unsigned short*)(w + off); off = align256(off + (size_t)65536 * 2);
    (void)ws_size;

    int gE = (E + 255) / 256;
    int gNode = (N + 3) / 4;
    int nb1024 = (N + 1023) / 1024;

    // 1) CSR build + weight splits
    hipMemsetAsync(indeg, 0, (size_t)N * 4, stream);
    hist_kernel<<<gE, 256, 0, stream>>>(edst, indeg, E);
    scan_partial<<<nb1024, 256, 0, stream>>>(indeg, bsums, N);
    scan_sums<<<1, 64, 0, stream>>>(bsums, nb1024);
    scan_final<<<nb1024, 256, 0, stream>>>(indeg, bsums, rowptr, cursor, dinv, N);
    scatter_kernel<<<gE, 256, 0, stream>>>(esrc, edst, cursor, col, E);
    split_w2_kernel<<<512, 256, 0, stream>>>(W1, w1h, w1l, W2, w2h, w2l);

    // 2) conv1: bufA = bf16(x @ W1); bufB = bf16(relu(agg(bufA) + b1))
    dim3 ggrid((N + 127) / 128, 2);
    gemm_splitA<<<ggrid, 256, 0, stream>>>(x, w1h, w1l, bufA, N);
    agg_bf16<<<gNode, 256, 0, stream>>>(bufA, rowptr, col, dinv, b1, bufB, N);

    // 3) conv2: bufA = bf16(bufB @ W2)
    gemm_exact<<<ggrid, 256, 0, stream>>>(bufB, w2h, w2l, bufA, N);

    // 4) agg2 + FC + log_softmax fused
    agg_fc_bf16<<<gNode, 256, 0, stream>>>(bufA, rowptr, col, dinv, b2, Wfc, bfc, out, N);
}